// Round 8
// baseline (6175.156 us; speedup 1.0000x reference)
//
#include <hip/hip_runtime.h>

// ---------------------------------------------------------------------------
// Encoder_conv: emb (1x1 conv) -> 3x { multi-tap K=2 convs summed -> LSTM scan
// with per-step attention gating }.
// B=32, W=512, H=256, 4H=1024, NINP=128, K=2, NLAYERS=3.
//
// Round 8: fix round-7's nc-tail bug (stored c_{509} for w=510; must be cx,
// which holds c_510 at top of iteration 511). Structure unchanged:
//  - AGPR weight residency via accvgpr_write/read (176 dw/thread)
//  - 16 dw/thread global (L1-resident, prefetched), 64 dw/thread LDS
//  - DPP cross-lane reduces (quad butterfly + row-reduce for attention)
//  - deferred attention gating; stores at top of next step; 1 barrier/step
// ---------------------------------------------------------------------------

typedef _Float16 h2 __attribute__((ext_vector_type(2)));

static __device__ __forceinline__ float fdot2(unsigned a, unsigned b, float c) {
#if __has_builtin(__builtin_amdgcn_fdot2)
  return __builtin_amdgcn_fdot2(__builtin_bit_cast(h2, a),
                                __builtin_bit_cast(h2, b), c, false);
#else
  h2 x = __builtin_bit_cast(h2, a), y = __builtin_bit_cast(h2, b);
  return c + (float)x[0] * (float)y[0] + (float)x[1] * (float)y[1];
#endif
}

// AGPR -> VGPR move (the residency mechanism the allocator can't undo).
static __device__ __forceinline__ unsigned aread(unsigned a) {
  unsigned v;
  asm volatile("v_accvgpr_read_b32 %0, %1" : "=v"(v) : "a"(a));
  return v;
}

// x + dpp(x). CTRL: 0xB1=quad xor1, 0x4E=quad xor2, 0x111/112/114/118=row_shr,
// 0x142=row_bcast15, 0x143=row_bcast31. bound_ctrl=true -> 0-fill.
template <int CTRL>
static __device__ __forceinline__ float dpp_add(float x) {
  int t = __builtin_amdgcn_update_dpp(0, __builtin_bit_cast(int, x), CTRL, 0xf,
                                      0xf, true);
  return x + __builtin_bit_cast(float, t);
}

static __device__ __forceinline__ unsigned short f16b(float v) {
  _Float16 h = (_Float16)v;
  return __builtin_bit_cast(unsigned short, h);
}

static __device__ __forceinline__ float sigm(float x) {
  return 1.0f / (1.0f + __expf(-x));
}
static __device__ __forceinline__ float tanh_(float x) {
  return 1.0f - 2.0f / (1.0f + __expf(2.0f * x));
}

// Packs rec_w per layer (131072 dwords/layer).
// Thread tid: s=tid&3, u=tid>>2; rows row=(rl>>1)*256+(rl&1)*128+u (rl=0..7).
// Slot (i,k): column quad qeff=(i+2s)&7 (bank derotation), cp=s*32+qeff*4+k.
//   AGPR  (176): i=0..4 all rl: d=rl*20+i*4+k          off = d*512+tid
//                i=5, rl=4..7 : d=160+(rl-4)*4+k       off = d*512+tid
//   GLOBAL (16): i=5, rl=0..3 : off = 90112 + rl*2048 + tid*4 + k
//   LDS    (64): i=6,7       : c=rl*2+(i-6), off = 98304 + c*2048 + tid*4 + k
__global__ __launch_bounds__(256) void prep_rw(const float* __restrict__ rw,
                                               unsigned* __restrict__ rwp) {
  int idx = blockIdx.x * 256 + threadIdx.x;
  if (idx >= 3 * 131072) return;
  int l = idx / 131072, pos = idx % 131072;
  int tid, rl, i, k;
  if (pos < 90112) {
    int d = pos >> 9;
    tid = pos & 511;
    if (d < 160) {
      rl = d / 20;
      int rem = d % 20;
      i = rem >> 2;
      k = rem & 3;
    } else {
      rl = 4 + ((d - 160) >> 2);
      i = 5;
      k = (d - 160) & 3;
    }
  } else if (pos < 98304) {
    int p = pos - 90112;
    rl = p >> 11;
    int rem = p & 2047;
    tid = rem >> 2;
    k = rem & 3;
    i = 5;
  } else {
    int p = pos - 98304;
    int c = p >> 11, rem = p & 2047;
    tid = rem >> 2;
    k = rem & 3;
    rl = c >> 1;
    i = 6 + (c & 1);
  }
  int s = tid & 3, u = tid >> 2;
  int row = (rl >> 1) * 256 + (rl & 1) * 128 + u;
  int qeff = (i + 2 * s) & 7;
  int cp = s * 32 + qeff * 4 + k;
  const float* src = rw + (l * 1024 + row) * 256 + 2 * cp;
  rwp[idx] = (unsigned)f16b(src[0]) | ((unsigned)f16b(src[1]) << 16);
}

// cwp[jj][o][k][d] = pack(f16(conv_w[jj][o][2d][k]), f16(conv_w[jj][o][2d+1][k]))
__global__ __launch_bounds__(256) void prep_cw(const float* __restrict__ cw,
                                               unsigned* __restrict__ cwp) {
  int idx = blockIdx.x * 256 + threadIdx.x;
  if (idx >= 6 * 1024 * 2 * 128) return;
  int d = idx & 127, k = (idx >> 7) & 1, o = (idx >> 8) & 1023, jj = idx >> 18;
  const float* src = cw + ((jj * 1024 + o) * 256 + 2 * d) * 2 + k;
  unsigned v = (unsigned)f16b(src[0]) | ((unsigned)f16b(src[2]) << 16);
  cwp[idx] = v;
}

// x0[b,w,h] = sum_c emb_w[h,c]*input[b,c,w] + emb_b[h]; store f16 + out tail.
__global__ __launch_bounds__(256) void emb_kernel(
    const float* __restrict__ inp, const float* __restrict__ ew,
    const float* __restrict__ eb, unsigned short* __restrict__ x0f,
    float* __restrict__ out) {
  __shared__ float xt[32][65];
  __shared__ float wt[64][33];
  int b = blockIdx.z, w0 = blockIdx.x * 64, h0 = blockIdx.y * 64;
  int tid = threadIdx.x, tx = tid & 15, ty = tid >> 4;
  float acc[4][4] = {};
  for (int c0 = 0; c0 < 128; c0 += 32) {
    __syncthreads();
#pragma unroll
    for (int i = 0; i < 8; i++) {
      int f = i * 256 + tid, c = f >> 6, wl = f & 63;
      xt[c][wl] = inp[(b * 128 + c0 + c) * 512 + w0 + wl];
    }
#pragma unroll
    for (int i = 0; i < 8; i++) {
      int f = i * 256 + tid, h = f >> 5, c = f & 31;
      wt[h][c] = ew[(h0 + h) * 128 + c0 + c];
    }
    __syncthreads();
#pragma unroll
    for (int c = 0; c < 32; c++) {
      float xv[4], wv[4];
#pragma unroll
      for (int q = 0; q < 4; q++) xv[q] = xt[c][ty * 4 + q];
#pragma unroll
      for (int p = 0; p < 4; p++) wv[p] = wt[tx * 4 + p][c];
#pragma unroll
      for (int q = 0; q < 4; q++)
#pragma unroll
        for (int p = 0; p < 4; p++) acc[q][p] += xv[q] * wv[p];
    }
  }
#pragma unroll
  for (int q = 0; q < 4; q++) {
    int w = w0 + ty * 4 + q;
#pragma unroll
    for (int p = 0; p < 4; p++) {
      int h = h0 + tx * 4 + p;
      float v = acc[q][p] + eb[h];
      x0f[(b * 512 + w) * 256 + h] = f16b(v);
      if (w >= 510) out[(b * 256 + h) * 2 + (w - 510)] = v;  // x[0] tail
    }
  }
}

// ig[b,w,o] = sum_j sum_{i,k} xpad_j[b,w-1+k,i] * cw[off+j][o,i,k] + biases
__global__ __launch_bounds__(256) void conv_kernel(
    const unsigned short* __restrict__ xf, const unsigned* __restrict__ cwp,
    const float* __restrict__ cb, const float* __restrict__ hidden,
    unsigned short* __restrict__ igf, int l, int off) {
  __shared__ __align__(16) unsigned xs[65][20];    // [pad-col][dw16], stride 20
  __shared__ __align__(16) unsigned wsm[2][16][66];// [k][dw16][o], pad 66
  int b = blockIdx.z, w0 = blockIdx.x * 64, o0 = blockIdx.y * 64;
  int tid = threadIdx.x, tx = tid & 15, ty = tid >> 4;
  float acc[4][4] = {};
  int nl = l + 1;
  for (int j = 0; j < nl; j++) {
    const unsigned* xj = (const unsigned*)(xf + j * 4194304 + b * 512 * 256);
    const unsigned* cwj = cwp + (off + j) * 262144;
    for (int c0 = 0; c0 < 256; c0 += 32) {
      int d0 = c0 >> 1;
      __syncthreads();
#pragma unroll
      for (int i = 0; i < 5; i++) {
        int f = i * 256 + tid;
        if (f < 1040) {
          int col = f >> 4, dw = f & 15;
          int w = w0 - 1 + col;
          unsigned v;
          if (w >= 0) {
            v = xj[w * 128 + d0 + dw];
          } else {  // left pad: hidden[j][b][i][1]
            const float* hp = hidden + ((j * 32 + b) * 256 + 2 * (d0 + dw)) * 2 + 1;
            v = (unsigned)f16b(hp[0]) | ((unsigned)f16b(hp[2]) << 16);
          }
          xs[col][dw] = v;
        }
      }
#pragma unroll
      for (int i = 0; i < 8; i++) {
        int f = i * 256 + tid;
        int oo = f >> 5, k = (f >> 4) & 1, dw = f & 15;
        wsm[k][dw][oo] = cwj[(o0 + oo) * 256 + k * 128 + d0 + dw];
      }
      __syncthreads();
#pragma unroll
      for (int g = 0; g < 4; g++) {
        uint4 xv[5];
#pragma unroll
        for (int q = 0; q < 5; q++)
          xv[q] = *(const uint4*)&xs[ty * 4 + q][g * 4];
#pragma unroll
        for (int p = 0; p < 4; p++) {
          unsigned wv0[4], wv1[4];
#pragma unroll
          for (int r = 0; r < 4; r++) {
            wv0[r] = wsm[0][g * 4 + r][tx * 4 + p];
            wv1[r] = wsm[1][g * 4 + r][tx * 4 + p];
          }
#pragma unroll
          for (int q = 0; q < 4; q++) {
            float a = acc[q][p];
            a = fdot2(wv0[0], xv[q].x, a);
            a = fdot2(wv0[1], xv[q].y, a);
            a = fdot2(wv0[2], xv[q].z, a);
            a = fdot2(wv0[3], xv[q].w, a);
            a = fdot2(wv1[0], xv[q + 1].x, a);
            a = fdot2(wv1[1], xv[q + 1].y, a);
            a = fdot2(wv1[2], xv[q + 1].z, a);
            a = fdot2(wv1[3], xv[q + 1].w, a);
            acc[q][p] = a;
          }
        }
      }
    }
  }
#pragma unroll
  for (int p = 0; p < 4; p++) {
    int o = o0 + tx * 4 + p;
    float bias = 0.f;
    for (int j = 0; j < nl; j++) bias += cb[(off + j) * 1024 + o];
#pragma unroll
    for (int q = 0; q < 4; q++) {
      int w = w0 + ty * 4 + q;
      igf[(b * 512 + w) * 1024 + o] = f16b(acc[q][p] + bias);
    }
  }
}

// One WG per batch; 512 threads; lane (s=tid&3, u=tid>>2) computes 8 partial
// row-dots over 1/4 of hx, DPP-butterfly-reduced in-quad. 1 barrier/step.
__global__ __launch_bounds__(512)
__attribute__((amdgpu_waves_per_eu(2, 2)))
void rec_kernel(const _Float16* __restrict__ igf, const unsigned* __restrict__ rwp_l,
                const float* __restrict__ rb, const float* __restrict__ aw,
                const float* __restrict__ hidden, const float* __restrict__ context,
                int l, unsigned short* __restrict__ xnext, float* __restrict__ out) {
  __shared__ __align__(16) uint4 w_lds4[16 * 512];          // 128 KB
  __shared__ __align__(16) unsigned short hx_buf[2][256];   // double-buffered raw h
  __shared__ float red[2][8];                               // double-buffered attn partials
  int b = blockIdx.x, tid = threadIdx.x;
  int s = tid & 3, u = tid >> 2, lane = tid & 63, wid = tid >> 6;
  int hh = s & 1;
  int u2 = u + 128 * hh;  // this lane's unit

  // 176 weight dwords -> AGPRs
  unsigned wa[176];
#pragma unroll
  for (int d = 0; d < 176; d++) {
    unsigned v = rwp_l[d * 512 + tid];
    asm volatile("v_accvgpr_write_b32 %0, %1" : "=a"(wa[d]) : "v"(v));
  }

  // 64 weight dwords -> LDS (conflict-free b128)
  {
    const uint4* g16 = (const uint4*)(rwp_l + 98304);
#pragma unroll
    for (int c = 0; c < 16; c++) w_lds4[c * 512 + tid] = g16[c * 512 + tid];
  }
  const uint4* gq = ((const uint4*)rwp_l) + 22528;  // 16 dw/thread, slot 5 rl<4

  // bank-derotated hx quad byte-offsets (slot i -> quad 8s + ((i+2s)&7))
  int qoff[8];
#pragma unroll
  for (int i = 0; i < 8; i++) qoff[i] = (8 * s + ((i + 2 * s) & 7)) * 16;

  float rb0 = rb[u2], rb1 = rb[256 + u2], rb2 = rb[512 + u2], rb3 = rb[768 + u2];
  float awj = aw[u2];
  float cx = context[((l * 32 + b) * 256 + u2) * 2 + 1];
  if (tid < 256)
    hx_buf[1][tid] = f16b(hidden[(((l + 1) * 32 + b) * 256 + tid) * 2 + 1]);
  float h_prev = 0.f;
  __syncthreads();

  const _Float16* igb = igf + (b * 512) * 1024 + u2;

  for (int t = 0; t < 512; t++) {
    int cur = t & 1, prv = cur ^ 1;
    // m = a_(t-1) (deferred gating: dot(w, a*h) = a*dot(w,h)) + stores for t-1
    float m_ = 1.0f;
    if (t) {
      const float* rp = red[prv];
      m_ = sigm(((rp[0] + rp[1]) + (rp[2] + rp[3])) +
                ((rp[4] + rp[5]) + (rp[6] + rp[7])));
      if (s < 2) {
        float hg = h_prev * m_;
        xnext[(b * 512 + (t - 1)) * 256 + u2] = f16b(hg);
        if (t == 511) {
          out[(((l + 1) * 32 + b) * 256 + u2) * 2 + 0] = hg;      // x w=510
          // cx here still holds c_510 (this iteration hasn't updated it yet)
          out[65536 + ((l * 32 + b) * 256 + u2) * 2 + 0] = cx;    // nc w=510
        }
      }
      if (tid == 0) out[114688 + (l * 32 + b) * 511 + (t - 1)] = m_;   // attn
    }
    // ig + global-weight prefetch (consumed ~1500 cyc later)
    const _Float16* ip = igb + t * 1024;
    float ig0 = (float)ip[0], ig1 = (float)ip[256];
    float ig2 = (float)ip[512], ig3 = (float)ip[768];
    uint4 gw0 = gq[tid], gw1 = gq[512 + tid], gw2 = gq[1024 + tid],
          gw3 = gq[1536 + tid];

    float acc[8] = {};
    const char* hb = (const char*)hx_buf[prv];
#pragma unroll
    for (int i = 0; i < 5; i++) {
      uint4 h = *(const uint4*)(hb + qoff[i]);
#pragma unroll
      for (int rl = 0; rl < 8; rl++) {
        acc[rl] = fdot2(aread(wa[rl * 20 + i * 4 + 0]), h.x, acc[rl]);
        acc[rl] = fdot2(aread(wa[rl * 20 + i * 4 + 1]), h.y, acc[rl]);
        acc[rl] = fdot2(aread(wa[rl * 20 + i * 4 + 2]), h.z, acc[rl]);
        acc[rl] = fdot2(aread(wa[rl * 20 + i * 4 + 3]), h.w, acc[rl]);
      }
    }
    {
      uint4 h = *(const uint4*)(hb + qoff[5]);
      acc[0] = fdot2(gw0.x, h.x, acc[0]);
      acc[0] = fdot2(gw0.y, h.y, acc[0]);
      acc[0] = fdot2(gw0.z, h.z, acc[0]);
      acc[0] = fdot2(gw0.w, h.w, acc[0]);
      acc[1] = fdot2(gw1.x, h.x, acc[1]);
      acc[1] = fdot2(gw1.y, h.y, acc[1]);
      acc[1] = fdot2(gw1.z, h.z, acc[1]);
      acc[1] = fdot2(gw1.w, h.w, acc[1]);
      acc[2] = fdot2(gw2.x, h.x, acc[2]);
      acc[2] = fdot2(gw2.y, h.y, acc[2]);
      acc[2] = fdot2(gw2.z, h.z, acc[2]);
      acc[2] = fdot2(gw2.w, h.w, acc[2]);
      acc[3] = fdot2(gw3.x, h.x, acc[3]);
      acc[3] = fdot2(gw3.y, h.y, acc[3]);
      acc[3] = fdot2(gw3.z, h.z, acc[3]);
      acc[3] = fdot2(gw3.w, h.w, acc[3]);
#pragma unroll
      for (int rl = 4; rl < 8; rl++) {
        acc[rl] = fdot2(aread(wa[160 + (rl - 4) * 4 + 0]), h.x, acc[rl]);
        acc[rl] = fdot2(aread(wa[160 + (rl - 4) * 4 + 1]), h.y, acc[rl]);
        acc[rl] = fdot2(aread(wa[160 + (rl - 4) * 4 + 2]), h.z, acc[rl]);
        acc[rl] = fdot2(aread(wa[160 + (rl - 4) * 4 + 3]), h.w, acc[rl]);
      }
    }
#pragma unroll
    for (int i = 6; i < 8; i++) {
      uint4 h = *(const uint4*)(hb + qoff[i]);
#pragma unroll
      for (int rl = 0; rl < 8; rl++) {
        uint4 lw = w_lds4[(rl * 2 + (i - 6)) * 512 + tid];
        acc[rl] = fdot2(lw.x, h.x, acc[rl]);
        acc[rl] = fdot2(lw.y, h.y, acc[rl]);
        acc[rl] = fdot2(lw.z, h.z, acc[rl]);
        acc[rl] = fdot2(lw.w, h.w, acc[rl]);
      }
    }
    // butterfly over s via DPP quad_perm (xor1 then xor2): all 4 lanes of a
    // quad end with identical full sums (commutative adds, bit-identical)
#pragma unroll
    for (int rl = 0; rl < 8; rl++) acc[rl] = dpp_add<0xB1>(acc[rl]);
#pragma unroll
    for (int rl = 0; rl < 8; rl++) acc[rl] = dpp_add<0x4E>(acc[rl]);

    // this lane's 4 gates (rows g*256 + u2 <-> acc[g*2+hh])
    float di = hh ? acc[1] : acc[0];
    float df = hh ? acc[3] : acc[2];
    float dc = hh ? acc[5] : acc[4];
    float do_ = hh ? acc[7] : acc[6];
    float g_i = ig0 + rb0 + m_ * di;
    float g_f = ig1 + rb1 + m_ * df;
    float g_c = ig2 + rb2 + m_ * dc;
    float g_o = ig3 + rb3 + m_ * do_;
    cx = sigm(g_f) * cx + sigm(g_i) * tanh_(g_c);
    float h_raw = sigm(g_o) * tanh_(cx);

    // hx write FIRST (keeps DS queue short before the barrier)
    if (s < 2) hx_buf[cur][u2] = f16b(h_raw);

    // attention partial: full-wave DPP sum -> lane 63
    float part = (s < 2) ? h_raw * awj : 0.f;
    part = dpp_add<0x111>(part);
    part = dpp_add<0x112>(part);
    part = dpp_add<0x114>(part);
    part = dpp_add<0x118>(part);
    part = dpp_add<0x142>(part);
    part = dpp_add<0x143>(part);
    if (lane == 63) red[cur][wid] = part;

    h_prev = h_raw;
    __syncthreads();
  }
  // flush last step (ungated)
  if (s < 2) {
    xnext[(b * 512 + 511) * 256 + u2] = f16b(h_prev);
    out[(((l + 1) * 32 + b) * 256 + u2) * 2 + 1] = h_prev;       // x w=511
    out[65536 + ((l * 32 + b) * 256 + u2) * 2 + 1] = cx;         // nc w=511
  }
}

extern "C" void kernel_launch(void* const* d_in, const int* in_sizes, int n_in,
                              void* d_out, int out_size, void* d_ws,
                              size_t ws_size, hipStream_t stream) {
  const float* input  = (const float*)d_in[0];
  const float* hidden = (const float*)d_in[1];
  const float* context= (const float*)d_in[2];
  const float* emb_w  = (const float*)d_in[3];
  const float* emb_b  = (const float*)d_in[4];
  const float* conv_w = (const float*)d_in[5];
  const float* conv_b = (const float*)d_in[6];
  const float* rec_w  = (const float*)d_in[7];
  const float* rec_b  = (const float*)d_in[8];
  const float* attn_w = (const float*)d_in[9];
  float* out = (float*)d_out;

  char* ws = (char*)d_ws;
  unsigned short* xf16 = (unsigned short*)ws;                    // 4 x 4,194,304 f16 = 32 MB
  _Float16* igf = (_Float16*)(ws + 33554432);                    // 16,777,216 f16 = 32 MB
  unsigned* rwp = (unsigned*)(ws + 67108864);                    // 1.5 MB
  unsigned* cwp = (unsigned*)(ws + 68681728);                    // 6 MB

  hipLaunchKernelGGL(prep_rw, dim3(1536), dim3(256), 0, stream, rec_w, rwp);
  hipLaunchKernelGGL(prep_cw, dim3(6144), dim3(256), 0, stream, conv_w, cwp);
  hipLaunchKernelGGL(emb_kernel, dim3(8, 4, 32), dim3(256), 0, stream,
                     input, emb_w, emb_b, xf16, out);
  int off = 0;
  for (int l = 0; l < 3; l++) {
    hipLaunchKernelGGL(conv_kernel, dim3(8, 16, 32), dim3(256), 0, stream,
                       xf16, cwp, conv_b, hidden, (unsigned short*)igf, l, off);
    hipLaunchKernelGGL(rec_kernel, dim3(32), dim3(512), 0, stream,
                       igf, rwp + l * 131072, rec_b + l * 1024,
                       attn_w + l * 256, hidden, context, l,
                       xf16 + (l + 1) * 4194304, out);
    off += l + 1;
  }
}

// Round 9
// 5748.845 us; speedup vs baseline: 1.0742x; 1.0742x over previous
//
#include <hip/hip_runtime.h>

// ---------------------------------------------------------------------------
// Encoder_conv: emb (1x1 conv) -> 3x { multi-tap K=2 convs summed -> LSTM scan
// with per-step attention gating }.
// B=32, W=512, H=256, 4H=1024, NINP=128, K=2, NLAYERS=3.
//
// Round 9: identical to round 8 EXCEPT aread() is non-volatile and reads are
// grouped 4-ahead-of-4-dots. Round 8's `asm volatile` pinned program order of
// 176 read->dot dependent pairs (~+1200 cyc/wave stall); non-volatile pure
// asm lets the scheduler interleave next row's reads under current row's dots.
//  - AGPR weight residency (176 dw/thread), 16 dw global prefetch, 64 dw LDS
//  - DPP cross-lane reduces; deferred attention gating; 1 barrier/step
// ---------------------------------------------------------------------------

typedef _Float16 h2 __attribute__((ext_vector_type(2)));

static __device__ __forceinline__ float fdot2(unsigned a, unsigned b, float c) {
#if __has_builtin(__builtin_amdgcn_fdot2)
  return __builtin_amdgcn_fdot2(__builtin_bit_cast(h2, a),
                                __builtin_bit_cast(h2, b), c, false);
#else
  h2 x = __builtin_bit_cast(h2, a), y = __builtin_bit_cast(h2, b);
  return c + (float)x[0] * (float)y[0] + (float)x[1] * (float)y[1];
#endif
}

// AGPR -> VGPR move. NON-volatile: pure value move, freely schedulable;
// residency is still enforced by the "a" register class itself.
static __device__ __forceinline__ unsigned aread(unsigned a) {
  unsigned v;
  asm("v_accvgpr_read_b32 %0, %1" : "=v"(v) : "a"(a));
  return v;
}

// x + dpp(x). CTRL: 0xB1=quad xor1, 0x4E=quad xor2, 0x111/112/114/118=row_shr,
// 0x142=row_bcast15, 0x143=row_bcast31. bound_ctrl=true -> 0-fill.
template <int CTRL>
static __device__ __forceinline__ float dpp_add(float x) {
  int t = __builtin_amdgcn_update_dpp(0, __builtin_bit_cast(int, x), CTRL, 0xf,
                                      0xf, true);
  return x + __builtin_bit_cast(float, t);
}

static __device__ __forceinline__ unsigned short f16b(float v) {
  _Float16 h = (_Float16)v;
  return __builtin_bit_cast(unsigned short, h);
}

static __device__ __forceinline__ float sigm(float x) {
  return 1.0f / (1.0f + __expf(-x));
}
static __device__ __forceinline__ float tanh_(float x) {
  return 1.0f - 2.0f / (1.0f + __expf(2.0f * x));
}

// Packs rec_w per layer (131072 dwords/layer).
// Thread tid: s=tid&3, u=tid>>2; rows row=(rl>>1)*256+(rl&1)*128+u (rl=0..7).
// Slot (i,k): column quad qeff=(i+2s)&7 (bank derotation), cp=s*32+qeff*4+k.
//   AGPR  (176): i=0..4 all rl: d=rl*20+i*4+k          off = d*512+tid
//                i=5, rl=4..7 : d=160+(rl-4)*4+k       off = d*512+tid
//   GLOBAL (16): i=5, rl=0..3 : off = 90112 + rl*2048 + tid*4 + k
//   LDS    (64): i=6,7       : c=rl*2+(i-6), off = 98304 + c*2048 + tid*4 + k
__global__ __launch_bounds__(256) void prep_rw(const float* __restrict__ rw,
                                               unsigned* __restrict__ rwp) {
  int idx = blockIdx.x * 256 + threadIdx.x;
  if (idx >= 3 * 131072) return;
  int l = idx / 131072, pos = idx % 131072;
  int tid, rl, i, k;
  if (pos < 90112) {
    int d = pos >> 9;
    tid = pos & 511;
    if (d < 160) {
      rl = d / 20;
      int rem = d % 20;
      i = rem >> 2;
      k = rem & 3;
    } else {
      rl = 4 + ((d - 160) >> 2);
      i = 5;
      k = (d - 160) & 3;
    }
  } else if (pos < 98304) {
    int p = pos - 90112;
    rl = p >> 11;
    int rem = p & 2047;
    tid = rem >> 2;
    k = rem & 3;
    i = 5;
  } else {
    int p = pos - 98304;
    int c = p >> 11, rem = p & 2047;
    tid = rem >> 2;
    k = rem & 3;
    rl = c >> 1;
    i = 6 + (c & 1);
  }
  int s = tid & 3, u = tid >> 2;
  int row = (rl >> 1) * 256 + (rl & 1) * 128 + u;
  int qeff = (i + 2 * s) & 7;
  int cp = s * 32 + qeff * 4 + k;
  const float* src = rw + (l * 1024 + row) * 256 + 2 * cp;
  rwp[idx] = (unsigned)f16b(src[0]) | ((unsigned)f16b(src[1]) << 16);
}

// cwp[jj][o][k][d] = pack(f16(conv_w[jj][o][2d][k]), f16(conv_w[jj][o][2d+1][k]))
__global__ __launch_bounds__(256) void prep_cw(const float* __restrict__ cw,
                                               unsigned* __restrict__ cwp) {
  int idx = blockIdx.x * 256 + threadIdx.x;
  if (idx >= 6 * 1024 * 2 * 128) return;
  int d = idx & 127, k = (idx >> 7) & 1, o = (idx >> 8) & 1023, jj = idx >> 18;
  const float* src = cw + ((jj * 1024 + o) * 256 + 2 * d) * 2 + k;
  unsigned v = (unsigned)f16b(src[0]) | ((unsigned)f16b(src[2]) << 16);
  cwp[idx] = v;
}

// x0[b,w,h] = sum_c emb_w[h,c]*input[b,c,w] + emb_b[h]; store f16 + out tail.
__global__ __launch_bounds__(256) void emb_kernel(
    const float* __restrict__ inp, const float* __restrict__ ew,
    const float* __restrict__ eb, unsigned short* __restrict__ x0f,
    float* __restrict__ out) {
  __shared__ float xt[32][65];
  __shared__ float wt[64][33];
  int b = blockIdx.z, w0 = blockIdx.x * 64, h0 = blockIdx.y * 64;
  int tid = threadIdx.x, tx = tid & 15, ty = tid >> 4;
  float acc[4][4] = {};
  for (int c0 = 0; c0 < 128; c0 += 32) {
    __syncthreads();
#pragma unroll
    for (int i = 0; i < 8; i++) {
      int f = i * 256 + tid, c = f >> 6, wl = f & 63;
      xt[c][wl] = inp[(b * 128 + c0 + c) * 512 + w0 + wl];
    }
#pragma unroll
    for (int i = 0; i < 8; i++) {
      int f = i * 256 + tid, h = f >> 5, c = f & 31;
      wt[h][c] = ew[(h0 + h) * 128 + c0 + c];
    }
    __syncthreads();
#pragma unroll
    for (int c = 0; c < 32; c++) {
      float xv[4], wv[4];
#pragma unroll
      for (int q = 0; q < 4; q++) xv[q] = xt[c][ty * 4 + q];
#pragma unroll
      for (int p = 0; p < 4; p++) wv[p] = wt[tx * 4 + p][c];
#pragma unroll
      for (int q = 0; q < 4; q++)
#pragma unroll
        for (int p = 0; p < 4; p++) acc[q][p] += xv[q] * wv[p];
    }
  }
#pragma unroll
  for (int q = 0; q < 4; q++) {
    int w = w0 + ty * 4 + q;
#pragma unroll
    for (int p = 0; p < 4; p++) {
      int h = h0 + tx * 4 + p;
      float v = acc[q][p] + eb[h];
      x0f[(b * 512 + w) * 256 + h] = f16b(v);
      if (w >= 510) out[(b * 256 + h) * 2 + (w - 510)] = v;  // x[0] tail
    }
  }
}

// ig[b,w,o] = sum_j sum_{i,k} xpad_j[b,w-1+k,i] * cw[off+j][o,i,k] + biases
__global__ __launch_bounds__(256) void conv_kernel(
    const unsigned short* __restrict__ xf, const unsigned* __restrict__ cwp,
    const float* __restrict__ cb, const float* __restrict__ hidden,
    unsigned short* __restrict__ igf, int l, int off) {
  __shared__ __align__(16) unsigned xs[65][20];    // [pad-col][dw16], stride 20
  __shared__ __align__(16) unsigned wsm[2][16][66];// [k][dw16][o], pad 66
  int b = blockIdx.z, w0 = blockIdx.x * 64, o0 = blockIdx.y * 64;
  int tid = threadIdx.x, tx = tid & 15, ty = tid >> 4;
  float acc[4][4] = {};
  int nl = l + 1;
  for (int j = 0; j < nl; j++) {
    const unsigned* xj = (const unsigned*)(xf + j * 4194304 + b * 512 * 256);
    const unsigned* cwj = cwp + (off + j) * 262144;
    for (int c0 = 0; c0 < 256; c0 += 32) {
      int d0 = c0 >> 1;
      __syncthreads();
#pragma unroll
      for (int i = 0; i < 5; i++) {
        int f = i * 256 + tid;
        if (f < 1040) {
          int col = f >> 4, dw = f & 15;
          int w = w0 - 1 + col;
          unsigned v;
          if (w >= 0) {
            v = xj[w * 128 + d0 + dw];
          } else {  // left pad: hidden[j][b][i][1]
            const float* hp = hidden + ((j * 32 + b) * 256 + 2 * (d0 + dw)) * 2 + 1;
            v = (unsigned)f16b(hp[0]) | ((unsigned)f16b(hp[2]) << 16);
          }
          xs[col][dw] = v;
        }
      }
#pragma unroll
      for (int i = 0; i < 8; i++) {
        int f = i * 256 + tid;
        int oo = f >> 5, k = (f >> 4) & 1, dw = f & 15;
        wsm[k][dw][oo] = cwj[(o0 + oo) * 256 + k * 128 + d0 + dw];
      }
      __syncthreads();
#pragma unroll
      for (int g = 0; g < 4; g++) {
        uint4 xv[5];
#pragma unroll
        for (int q = 0; q < 5; q++)
          xv[q] = *(const uint4*)&xs[ty * 4 + q][g * 4];
#pragma unroll
        for (int p = 0; p < 4; p++) {
          unsigned wv0[4], wv1[4];
#pragma unroll
          for (int r = 0; r < 4; r++) {
            wv0[r] = wsm[0][g * 4 + r][tx * 4 + p];
            wv1[r] = wsm[1][g * 4 + r][tx * 4 + p];
          }
#pragma unroll
          for (int q = 0; q < 4; q++) {
            float a = acc[q][p];
            a = fdot2(wv0[0], xv[q].x, a);
            a = fdot2(wv0[1], xv[q].y, a);
            a = fdot2(wv0[2], xv[q].z, a);
            a = fdot2(wv0[3], xv[q].w, a);
            a = fdot2(wv1[0], xv[q + 1].x, a);
            a = fdot2(wv1[1], xv[q + 1].y, a);
            a = fdot2(wv1[2], xv[q + 1].z, a);
            a = fdot2(wv1[3], xv[q + 1].w, a);
            acc[q][p] = a;
          }
        }
      }
    }
  }
#pragma unroll
  for (int p = 0; p < 4; p++) {
    int o = o0 + tx * 4 + p;
    float bias = 0.f;
    for (int j = 0; j < nl; j++) bias += cb[(off + j) * 1024 + o];
#pragma unroll
    for (int q = 0; q < 4; q++) {
      int w = w0 + ty * 4 + q;
      igf[(b * 512 + w) * 1024 + o] = f16b(acc[q][p] + bias);
    }
  }
}

// One WG per batch; 512 threads; lane (s=tid&3, u=tid>>2) computes 8 partial
// row-dots over 1/4 of hx, DPP-butterfly-reduced in-quad. 1 barrier/step.
__global__ __launch_bounds__(512)
__attribute__((amdgpu_waves_per_eu(2, 2)))
void rec_kernel(const _Float16* __restrict__ igf, const unsigned* __restrict__ rwp_l,
                const float* __restrict__ rb, const float* __restrict__ aw,
                const float* __restrict__ hidden, const float* __restrict__ context,
                int l, unsigned short* __restrict__ xnext, float* __restrict__ out) {
  __shared__ __align__(16) uint4 w_lds4[16 * 512];          // 128 KB
  __shared__ __align__(16) unsigned short hx_buf[2][256];   // double-buffered raw h
  __shared__ float red[2][8];                               // double-buffered attn partials
  int b = blockIdx.x, tid = threadIdx.x;
  int s = tid & 3, u = tid >> 2, lane = tid & 63, wid = tid >> 6;
  int hh = s & 1;
  int u2 = u + 128 * hh;  // this lane's unit

  // 176 weight dwords -> AGPRs (writes stay volatile: one-time init, must not
  // be sunk or reordered past the loop)
  unsigned wa[176];
#pragma unroll
  for (int d = 0; d < 176; d++) {
    unsigned v = rwp_l[d * 512 + tid];
    asm volatile("v_accvgpr_write_b32 %0, %1" : "=a"(wa[d]) : "v"(v));
  }

  // 64 weight dwords -> LDS (conflict-free b128)
  {
    const uint4* g16 = (const uint4*)(rwp_l + 98304);
#pragma unroll
    for (int c = 0; c < 16; c++) w_lds4[c * 512 + tid] = g16[c * 512 + tid];
  }
  const uint4* gq = ((const uint4*)rwp_l) + 22528;  // 16 dw/thread, slot 5 rl<4

  // bank-derotated hx quad byte-offsets (slot i -> quad 8s + ((i+2s)&7))
  int qoff[8];
#pragma unroll
  for (int i = 0; i < 8; i++) qoff[i] = (8 * s + ((i + 2 * s) & 7)) * 16;

  float rb0 = rb[u2], rb1 = rb[256 + u2], rb2 = rb[512 + u2], rb3 = rb[768 + u2];
  float awj = aw[u2];
  float cx = context[((l * 32 + b) * 256 + u2) * 2 + 1];
  if (tid < 256)
    hx_buf[1][tid] = f16b(hidden[(((l + 1) * 32 + b) * 256 + tid) * 2 + 1]);
  float h_prev = 0.f;
  __syncthreads();

  const _Float16* igb = igf + (b * 512) * 1024 + u2;

  for (int t = 0; t < 512; t++) {
    int cur = t & 1, prv = cur ^ 1;
    // m = a_(t-1) (deferred gating: dot(w, a*h) = a*dot(w,h)) + stores for t-1
    float m_ = 1.0f;
    if (t) {
      const float* rp = red[prv];
      m_ = sigm(((rp[0] + rp[1]) + (rp[2] + rp[3])) +
                ((rp[4] + rp[5]) + (rp[6] + rp[7])));
      if (s < 2) {
        float hg = h_prev * m_;
        xnext[(b * 512 + (t - 1)) * 256 + u2] = f16b(hg);
        if (t == 511) {
          out[(((l + 1) * 32 + b) * 256 + u2) * 2 + 0] = hg;      // x w=510
          // cx here still holds c_510 (this iteration hasn't updated it yet)
          out[65536 + ((l * 32 + b) * 256 + u2) * 2 + 0] = cx;    // nc w=510
        }
      }
      if (tid == 0) out[114688 + (l * 32 + b) * 511 + (t - 1)] = m_;   // attn
    }
    // ig + global-weight prefetch (consumed ~1500 cyc later)
    const _Float16* ip = igb + t * 1024;
    float ig0 = (float)ip[0], ig1 = (float)ip[256];
    float ig2 = (float)ip[512], ig3 = (float)ip[768];
    uint4 gw0 = gq[tid], gw1 = gq[512 + tid], gw2 = gq[1024 + tid],
          gw3 = gq[1536 + tid];

    float acc[8] = {};
    const char* hb = (const char*)hx_buf[prv];
#pragma unroll
    for (int i = 0; i < 5; i++) {
      uint4 h = *(const uint4*)(hb + qoff[i]);
#pragma unroll
      for (int rl = 0; rl < 8; rl++) {
        unsigned w0_ = aread(wa[rl * 20 + i * 4 + 0]);
        unsigned w1_ = aread(wa[rl * 20 + i * 4 + 1]);
        unsigned w2_ = aread(wa[rl * 20 + i * 4 + 2]);
        unsigned w3_ = aread(wa[rl * 20 + i * 4 + 3]);
        acc[rl] = fdot2(w0_, h.x, acc[rl]);
        acc[rl] = fdot2(w1_, h.y, acc[rl]);
        acc[rl] = fdot2(w2_, h.z, acc[rl]);
        acc[rl] = fdot2(w3_, h.w, acc[rl]);
      }
    }
    {
      uint4 h = *(const uint4*)(hb + qoff[5]);
      acc[0] = fdot2(gw0.x, h.x, acc[0]);
      acc[0] = fdot2(gw0.y, h.y, acc[0]);
      acc[0] = fdot2(gw0.z, h.z, acc[0]);
      acc[0] = fdot2(gw0.w, h.w, acc[0]);
      acc[1] = fdot2(gw1.x, h.x, acc[1]);
      acc[1] = fdot2(gw1.y, h.y, acc[1]);
      acc[1] = fdot2(gw1.z, h.z, acc[1]);
      acc[1] = fdot2(gw1.w, h.w, acc[1]);
      acc[2] = fdot2(gw2.x, h.x, acc[2]);
      acc[2] = fdot2(gw2.y, h.y, acc[2]);
      acc[2] = fdot2(gw2.z, h.z, acc[2]);
      acc[2] = fdot2(gw2.w, h.w, acc[2]);
      acc[3] = fdot2(gw3.x, h.x, acc[3]);
      acc[3] = fdot2(gw3.y, h.y, acc[3]);
      acc[3] = fdot2(gw3.z, h.z, acc[3]);
      acc[3] = fdot2(gw3.w, h.w, acc[3]);
#pragma unroll
      for (int rl = 4; rl < 8; rl++) {
        unsigned w0_ = aread(wa[160 + (rl - 4) * 4 + 0]);
        unsigned w1_ = aread(wa[160 + (rl - 4) * 4 + 1]);
        unsigned w2_ = aread(wa[160 + (rl - 4) * 4 + 2]);
        unsigned w3_ = aread(wa[160 + (rl - 4) * 4 + 3]);
        acc[rl] = fdot2(w0_, h.x, acc[rl]);
        acc[rl] = fdot2(w1_, h.y, acc[rl]);
        acc[rl] = fdot2(w2_, h.z, acc[rl]);
        acc[rl] = fdot2(w3_, h.w, acc[rl]);
      }
    }
#pragma unroll
    for (int i = 6; i < 8; i++) {
      uint4 h = *(const uint4*)(hb + qoff[i]);
#pragma unroll
      for (int rl = 0; rl < 8; rl++) {
        uint4 lw = w_lds4[(rl * 2 + (i - 6)) * 512 + tid];
        acc[rl] = fdot2(lw.x, h.x, acc[rl]);
        acc[rl] = fdot2(lw.y, h.y, acc[rl]);
        acc[rl] = fdot2(lw.z, h.z, acc[rl]);
        acc[rl] = fdot2(lw.w, h.w, acc[rl]);
      }
    }
    // butterfly over s via DPP quad_perm (xor1 then xor2): all 4 lanes of a
    // quad end with identical full sums (commutative adds, bit-identical)
#pragma unroll
    for (int rl = 0; rl < 8; rl++) acc[rl] = dpp_add<0xB1>(acc[rl]);
#pragma unroll
    for (int rl = 0; rl < 8; rl++) acc[rl] = dpp_add<0x4E>(acc[rl]);

    // this lane's 4 gates (rows g*256 + u2 <-> acc[g*2+hh])
    float di = hh ? acc[1] : acc[0];
    float df = hh ? acc[3] : acc[2];
    float dc = hh ? acc[5] : acc[4];
    float do_ = hh ? acc[7] : acc[6];
    float g_i = ig0 + rb0 + m_ * di;
    float g_f = ig1 + rb1 + m_ * df;
    float g_c = ig2 + rb2 + m_ * dc;
    float g_o = ig3 + rb3 + m_ * do_;
    cx = sigm(g_f) * cx + sigm(g_i) * tanh_(g_c);
    float h_raw = sigm(g_o) * tanh_(cx);

    // hx write FIRST (keeps DS queue short before the barrier)
    if (s < 2) hx_buf[cur][u2] = f16b(h_raw);

    // attention partial: full-wave DPP sum -> lane 63
    float part = (s < 2) ? h_raw * awj : 0.f;
    part = dpp_add<0x111>(part);
    part = dpp_add<0x112>(part);
    part = dpp_add<0x114>(part);
    part = dpp_add<0x118>(part);
    part = dpp_add<0x142>(part);
    part = dpp_add<0x143>(part);
    if (lane == 63) red[cur][wid] = part;

    h_prev = h_raw;
    __syncthreads();
  }
  // flush last step (ungated)
  if (s < 2) {
    xnext[(b * 512 + 511) * 256 + u2] = f16b(h_prev);
    out[(((l + 1) * 32 + b) * 256 + u2) * 2 + 1] = h_prev;       // x w=511
    out[65536 + ((l * 32 + b) * 256 + u2) * 2 + 1] = cx;         // nc w=511
  }
}

extern "C" void kernel_launch(void* const* d_in, const int* in_sizes, int n_in,
                              void* d_out, int out_size, void* d_ws,
                              size_t ws_size, hipStream_t stream) {
  const float* input  = (const float*)d_in[0];
  const float* hidden = (const float*)d_in[1];
  const float* context= (const float*)d_in[2];
  const float* emb_w  = (const float*)d_in[3];
  const float* emb_b  = (const float*)d_in[4];
  const float* conv_w = (const float*)d_in[5];
  const float* conv_b = (const float*)d_in[6];
  const float* rec_w  = (const float*)d_in[7];
  const float* rec_b  = (const float*)d_in[8];
  const float* attn_w = (const float*)d_in[9];
  float* out = (float*)d_out;

  char* ws = (char*)d_ws;
  unsigned short* xf16 = (unsigned short*)ws;                    // 4 x 4,194,304 f16 = 32 MB
  _Float16* igf = (_Float16*)(ws + 33554432);                    // 16,777,216 f16 = 32 MB
  unsigned* rwp = (unsigned*)(ws + 67108864);                    // 1.5 MB
  unsigned* cwp = (unsigned*)(ws + 68681728);                    // 6 MB

  hipLaunchKernelGGL(prep_rw, dim3(1536), dim3(256), 0, stream, rec_w, rwp);
  hipLaunchKernelGGL(prep_cw, dim3(6144), dim3(256), 0, stream, conv_w, cwp);
  hipLaunchKernelGGL(emb_kernel, dim3(8, 4, 32), dim3(256), 0, stream,
                     input, emb_w, emb_b, xf16, out);
  int off = 0;
  for (int l = 0; l < 3; l++) {
    hipLaunchKernelGGL(conv_kernel, dim3(8, 16, 32), dim3(256), 0, stream,
                       xf16, cwp, conv_b, hidden, (unsigned short*)igf, l, off);
    hipLaunchKernelGGL(rec_kernel, dim3(32), dim3(512), 0, stream,
                       igf, rwp + l * 131072, rec_b + l * 1024,
                       attn_w + l * 256, hidden, context, l,
                       xf16 + (l + 1) * 4194304, out);
    off += l + 1;
  }
}

// Round 10
// 4909.130 us; speedup vs baseline: 1.2579x; 1.1711x over previous
//
#include <hip/hip_runtime.h>

// ---------------------------------------------------------------------------
// Encoder_conv: emb (1x1 conv) -> 3x { multi-tap K=2 convs summed -> LSTM scan
// with per-step attention gating }.
// B=32, W=512, H=256, 4H=1024, NINP=128, K=2, NLAYERS=3.
//
// Round 10: occupancy ledger fix. r8/r9 ran 1 wave/SIMD: AGPR 176 + arch 128
// = 304 regs/lane > 256 (waves_per_eu budget doesn't count hand AGPRs).
// New split: AGPR 128 + arch <=128 = exactly 2 waves/SIMD.
//  weights/thread (8 rows x 8 quad-slots):
//   slots 0-3 -> AGPR (128 dw)   slots 4-5 -> global, re-read/step (64 dw,
//   coalesced b128, L1-resident) slots 6-7 -> LDS (128 KB, conflict-free)
//  structure from r9: DPP reduces, deferred gating, 1 barrier/step.
// ---------------------------------------------------------------------------

typedef _Float16 h2 __attribute__((ext_vector_type(2)));

static __device__ __forceinline__ float fdot2(unsigned a, unsigned b, float c) {
#if __has_builtin(__builtin_amdgcn_fdot2)
  return __builtin_amdgcn_fdot2(__builtin_bit_cast(h2, a),
                                __builtin_bit_cast(h2, b), c, false);
#else
  h2 x = __builtin_bit_cast(h2, a), y = __builtin_bit_cast(h2, b);
  return c + (float)x[0] * (float)y[0] + (float)x[1] * (float)y[1];
#endif
}

// AGPR -> VGPR move. Non-volatile: freely schedulable; residency enforced by
// the "a" register class.
static __device__ __forceinline__ unsigned aread(unsigned a) {
  unsigned v;
  asm("v_accvgpr_read_b32 %0, %1" : "=v"(v) : "a"(a));
  return v;
}

// x + dpp(x). CTRL: 0xB1=quad xor1, 0x4E=quad xor2, 0x111/112/114/118=row_shr,
// 0x142=row_bcast15, 0x143=row_bcast31. bound_ctrl=true -> 0-fill.
template <int CTRL>
static __device__ __forceinline__ float dpp_add(float x) {
  int t = __builtin_amdgcn_update_dpp(0, __builtin_bit_cast(int, x), CTRL, 0xf,
                                      0xf, true);
  return x + __builtin_bit_cast(float, t);
}

static __device__ __forceinline__ unsigned short f16b(float v) {
  _Float16 h = (_Float16)v;
  return __builtin_bit_cast(unsigned short, h);
}

static __device__ __forceinline__ float sigm(float x) {
  return 1.0f / (1.0f + __expf(-x));
}
static __device__ __forceinline__ float tanh_(float x) {
  return 1.0f - 2.0f / (1.0f + __expf(2.0f * x));
}

// Packs rec_w per layer (131072 dwords/layer).
// Thread tid: s=tid&3, u=tid>>2; rows row=(rl>>1)*256+(rl&1)*128+u (rl=0..7).
// Slot (i,k): column quad qeff=(i+2s)&7 (bank derotation), cp=s*32+qeff*4+k.
//   AGPR  (128): i=0..3: d = rl*16+i*4+k,     off = d*512 + tid
//   GLOBAL (64): i=4,5 : c = (i-4)*8+rl,      off = 65536 + c*2048 + tid*4 + k
//   LDS    (64): i=6,7 : c = rl*2+(i-6),      off = 98304 + c*2048 + tid*4 + k
__global__ __launch_bounds__(256) void prep_rw(const float* __restrict__ rw,
                                               unsigned* __restrict__ rwp) {
  int idx = blockIdx.x * 256 + threadIdx.x;
  if (idx >= 3 * 131072) return;
  int l = idx / 131072, pos = idx % 131072;
  int tid, rl, i, k;
  if (pos < 65536) {
    int d = pos >> 9;
    tid = pos & 511;
    rl = d >> 4;
    i = (d >> 2) & 3;
    k = d & 3;
  } else if (pos < 98304) {
    int p = pos - 65536;
    int c = p >> 11, rem = p & 2047;
    tid = rem >> 2;
    k = rem & 3;
    i = 4 + (c >> 3);
    rl = c & 7;
  } else {
    int p = pos - 98304;
    int c = p >> 11, rem = p & 2047;
    tid = rem >> 2;
    k = rem & 3;
    rl = c >> 1;
    i = 6 + (c & 1);
  }
  int s = tid & 3, u = tid >> 2;
  int row = (rl >> 1) * 256 + (rl & 1) * 128 + u;
  int qeff = (i + 2 * s) & 7;
  int cp = s * 32 + qeff * 4 + k;
  const float* src = rw + (l * 1024 + row) * 256 + 2 * cp;
  rwp[idx] = (unsigned)f16b(src[0]) | ((unsigned)f16b(src[1]) << 16);
}

// cwp[jj][o][k][d] = pack(f16(conv_w[jj][o][2d][k]), f16(conv_w[jj][o][2d+1][k]))
__global__ __launch_bounds__(256) void prep_cw(const float* __restrict__ cw,
                                               unsigned* __restrict__ cwp) {
  int idx = blockIdx.x * 256 + threadIdx.x;
  if (idx >= 6 * 1024 * 2 * 128) return;
  int d = idx & 127, k = (idx >> 7) & 1, o = (idx >> 8) & 1023, jj = idx >> 18;
  const float* src = cw + ((jj * 1024 + o) * 256 + 2 * d) * 2 + k;
  unsigned v = (unsigned)f16b(src[0]) | ((unsigned)f16b(src[2]) << 16);
  cwp[idx] = v;
}

// x0[b,w,h] = sum_c emb_w[h,c]*input[b,c,w] + emb_b[h]; store f16 + out tail.
__global__ __launch_bounds__(256) void emb_kernel(
    const float* __restrict__ inp, const float* __restrict__ ew,
    const float* __restrict__ eb, unsigned short* __restrict__ x0f,
    float* __restrict__ out) {
  __shared__ float xt[32][65];
  __shared__ float wt[64][33];
  int b = blockIdx.z, w0 = blockIdx.x * 64, h0 = blockIdx.y * 64;
  int tid = threadIdx.x, tx = tid & 15, ty = tid >> 4;
  float acc[4][4] = {};
  for (int c0 = 0; c0 < 128; c0 += 32) {
    __syncthreads();
#pragma unroll
    for (int i = 0; i < 8; i++) {
      int f = i * 256 + tid, c = f >> 6, wl = f & 63;
      xt[c][wl] = inp[(b * 128 + c0 + c) * 512 + w0 + wl];
    }
#pragma unroll
    for (int i = 0; i < 8; i++) {
      int f = i * 256 + tid, h = f >> 5, c = f & 31;
      wt[h][c] = ew[(h0 + h) * 128 + c0 + c];
    }
    __syncthreads();
#pragma unroll
    for (int c = 0; c < 32; c++) {
      float xv[4], wv[4];
#pragma unroll
      for (int q = 0; q < 4; q++) xv[q] = xt[c][ty * 4 + q];
#pragma unroll
      for (int p = 0; p < 4; p++) wv[p] = wt[tx * 4 + p][c];
#pragma unroll
      for (int q = 0; q < 4; q++)
#pragma unroll
        for (int p = 0; p < 4; p++) acc[q][p] += xv[q] * wv[p];
    }
  }
#pragma unroll
  for (int q = 0; q < 4; q++) {
    int w = w0 + ty * 4 + q;
#pragma unroll
    for (int p = 0; p < 4; p++) {
      int h = h0 + tx * 4 + p;
      float v = acc[q][p] + eb[h];
      x0f[(b * 512 + w) * 256 + h] = f16b(v);
      if (w >= 510) out[(b * 256 + h) * 2 + (w - 510)] = v;  // x[0] tail
    }
  }
}

// ig[b,w,o] = sum_j sum_{i,k} xpad_j[b,w-1+k,i] * cw[off+j][o,i,k] + biases
__global__ __launch_bounds__(256) void conv_kernel(
    const unsigned short* __restrict__ xf, const unsigned* __restrict__ cwp,
    const float* __restrict__ cb, const float* __restrict__ hidden,
    unsigned short* __restrict__ igf, int l, int off) {
  __shared__ __align__(16) unsigned xs[65][20];    // [pad-col][dw16], stride 20
  __shared__ __align__(16) unsigned wsm[2][16][66];// [k][dw16][o], pad 66
  int b = blockIdx.z, w0 = blockIdx.x * 64, o0 = blockIdx.y * 64;
  int tid = threadIdx.x, tx = tid & 15, ty = tid >> 4;
  float acc[4][4] = {};
  int nl = l + 1;
  for (int j = 0; j < nl; j++) {
    const unsigned* xj = (const unsigned*)(xf + j * 4194304 + b * 512 * 256);
    const unsigned* cwj = cwp + (off + j) * 262144;
    for (int c0 = 0; c0 < 256; c0 += 32) {
      int d0 = c0 >> 1;
      __syncthreads();
#pragma unroll
      for (int i = 0; i < 5; i++) {
        int f = i * 256 + tid;
        if (f < 1040) {
          int col = f >> 4, dw = f & 15;
          int w = w0 - 1 + col;
          unsigned v;
          if (w >= 0) {
            v = xj[w * 128 + d0 + dw];
          } else {  // left pad: hidden[j][b][i][1]
            const float* hp = hidden + ((j * 32 + b) * 256 + 2 * (d0 + dw)) * 2 + 1;
            v = (unsigned)f16b(hp[0]) | ((unsigned)f16b(hp[2]) << 16);
          }
          xs[col][dw] = v;
        }
      }
#pragma unroll
      for (int i = 0; i < 8; i++) {
        int f = i * 256 + tid;
        int oo = f >> 5, k = (f >> 4) & 1, dw = f & 15;
        wsm[k][dw][oo] = cwj[(o0 + oo) * 256 + k * 128 + d0 + dw];
      }
      __syncthreads();
#pragma unroll
      for (int g = 0; g < 4; g++) {
        uint4 xv[5];
#pragma unroll
        for (int q = 0; q < 5; q++)
          xv[q] = *(const uint4*)&xs[ty * 4 + q][g * 4];
#pragma unroll
        for (int p = 0; p < 4; p++) {
          unsigned wv0[4], wv1[4];
#pragma unroll
          for (int r = 0; r < 4; r++) {
            wv0[r] = wsm[0][g * 4 + r][tx * 4 + p];
            wv1[r] = wsm[1][g * 4 + r][tx * 4 + p];
          }
#pragma unroll
          for (int q = 0; q < 4; q++) {
            float a = acc[q][p];
            a = fdot2(wv0[0], xv[q].x, a);
            a = fdot2(wv0[1], xv[q].y, a);
            a = fdot2(wv0[2], xv[q].z, a);
            a = fdot2(wv0[3], xv[q].w, a);
            a = fdot2(wv1[0], xv[q + 1].x, a);
            a = fdot2(wv1[1], xv[q + 1].y, a);
            a = fdot2(wv1[2], xv[q + 1].z, a);
            a = fdot2(wv1[3], xv[q + 1].w, a);
            acc[q][p] = a;
          }
        }
      }
    }
  }
#pragma unroll
  for (int p = 0; p < 4; p++) {
    int o = o0 + tx * 4 + p;
    float bias = 0.f;
    for (int j = 0; j < nl; j++) bias += cb[(off + j) * 1024 + o];
#pragma unroll
    for (int q = 0; q < 4; q++) {
      int w = w0 + ty * 4 + q;
      igf[(b * 512 + w) * 1024 + o] = f16b(acc[q][p] + bias);
    }
  }
}

// One WG per batch; 512 threads; lane (s=tid&3, u=tid>>2) computes 8 partial
// row-dots over 1/4 of hx, DPP-butterfly-reduced in-quad. 1 barrier/step.
__global__ __launch_bounds__(512)
__attribute__((amdgpu_waves_per_eu(2, 2)))
void rec_kernel(const _Float16* __restrict__ igf, const unsigned* __restrict__ rwp_l,
                const float* __restrict__ rb, const float* __restrict__ aw,
                const float* __restrict__ hidden, const float* __restrict__ context,
                int l, unsigned short* __restrict__ xnext, float* __restrict__ out) {
  __shared__ __align__(16) uint4 w_lds4[16 * 512];          // 128 KB
  __shared__ __align__(16) unsigned short hx_buf[2][256];   // double-buffered raw h
  __shared__ float red[2][8];                               // double-buffered attn partials
  int b = blockIdx.x, tid = threadIdx.x;
  int s = tid & 3, u = tid >> 2, lane = tid & 63, wid = tid >> 6;
  int hh = s & 1;
  int u2 = u + 128 * hh;  // this lane's unit

  // 128 weight dwords -> AGPRs (volatile writes: one-time init, not sinkable)
  unsigned wa[128];
#pragma unroll
  for (int d = 0; d < 128; d++) {
    unsigned v = rwp_l[d * 512 + tid];
    asm volatile("v_accvgpr_write_b32 %0, %1" : "=a"(wa[d]) : "v"(v));
  }

  // 64 weight dwords -> LDS (conflict-free b128)
  {
    const uint4* g16 = (const uint4*)(rwp_l + 98304);
#pragma unroll
    for (int c = 0; c < 16; c++) w_lds4[c * 512 + tid] = g16[c * 512 + tid];
  }
  const uint4* gq = (const uint4*)(rwp_l + 65536);  // slots 4,5: [c][tid] uint4

  // bank-derotated hx quad byte-offsets (slot i -> quad 8s + ((i+2s)&7))
  int qoff[8];
#pragma unroll
  for (int i = 0; i < 8; i++) qoff[i] = (8 * s + ((i + 2 * s) & 7)) * 16;

  float rb0 = rb[u2], rb1 = rb[256 + u2], rb2 = rb[512 + u2], rb3 = rb[768 + u2];
  float awj = aw[u2];
  float cx = context[((l * 32 + b) * 256 + u2) * 2 + 1];
  if (tid < 256)
    hx_buf[1][tid] = f16b(hidden[(((l + 1) * 32 + b) * 256 + tid) * 2 + 1]);
  float h_prev = 0.f;
  __syncthreads();

  const _Float16* igb = igf + (b * 512) * 1024 + u2;

  for (int t = 0; t < 512; t++) {
    int cur = t & 1, prv = cur ^ 1;
    // m = a_(t-1) (deferred gating: dot(w, a*h) = a*dot(w,h)) + stores for t-1
    float m_ = 1.0f;
    if (t) {
      const float* rp = red[prv];
      m_ = sigm(((rp[0] + rp[1]) + (rp[2] + rp[3])) +
                ((rp[4] + rp[5]) + (rp[6] + rp[7])));
      if (s < 2) {
        float hg = h_prev * m_;
        xnext[(b * 512 + (t - 1)) * 256 + u2] = f16b(hg);
        if (t == 511) {
          out[(((l + 1) * 32 + b) * 256 + u2) * 2 + 0] = hg;      // x w=510
          // cx here still holds c_510 (this iteration hasn't updated it yet)
          out[65536 + ((l * 32 + b) * 256 + u2) * 2 + 0] = cx;    // nc w=510
        }
      }
      if (tid == 0) out[114688 + (l * 32 + b) * 511 + (t - 1)] = m_;   // attn
    }
    // ig + slot-4 weight prefetch (consumed after the AGPR slots)
    const _Float16* ip = igb + t * 1024;
    float ig0 = (float)ip[0], ig1 = (float)ip[256];
    float ig2 = (float)ip[512], ig3 = (float)ip[768];
    uint4 g4[8];
#pragma unroll
    for (int rl = 0; rl < 8; rl++) g4[rl] = gq[rl * 512 + tid];

    float acc[8] = {};
    const char* hb = (const char*)hx_buf[prv];
    // slots 0..3: AGPR weights (reads grouped, non-volatile -> schedulable)
#pragma unroll
    for (int i = 0; i < 4; i++) {
      uint4 h = *(const uint4*)(hb + qoff[i]);
#pragma unroll
      for (int rl = 0; rl < 8; rl++) {
        unsigned w0_ = aread(wa[rl * 16 + i * 4 + 0]);
        unsigned w1_ = aread(wa[rl * 16 + i * 4 + 1]);
        unsigned w2_ = aread(wa[rl * 16 + i * 4 + 2]);
        unsigned w3_ = aread(wa[rl * 16 + i * 4 + 3]);
        acc[rl] = fdot2(w0_, h.x, acc[rl]);
        acc[rl] = fdot2(w1_, h.y, acc[rl]);
        acc[rl] = fdot2(w2_, h.z, acc[rl]);
        acc[rl] = fdot2(w3_, h.w, acc[rl]);
      }
    }
    // slot 4: global weights (prefetched); issue slot-5 loads as we consume
    {
      uint4 h = *(const uint4*)(hb + qoff[4]);
#pragma unroll
      for (int rl = 0; rl < 8; rl++) {
        uint4 g5 = gq[(8 + rl) * 512 + tid];  // slot-5 load in flight
        uint4 w = g4[rl];
        acc[rl] = fdot2(w.x, h.x, acc[rl]);
        acc[rl] = fdot2(w.y, h.y, acc[rl]);
        acc[rl] = fdot2(w.z, h.z, acc[rl]);
        acc[rl] = fdot2(w.w, h.w, acc[rl]);
        g4[rl] = g5;  // reuse the register slot for slot 5
      }
    }
    // slot 5: global weights
    {
      uint4 h = *(const uint4*)(hb + qoff[5]);
#pragma unroll
      for (int rl = 0; rl < 8; rl++) {
        uint4 w = g4[rl];
        acc[rl] = fdot2(w.x, h.x, acc[rl]);
        acc[rl] = fdot2(w.y, h.y, acc[rl]);
        acc[rl] = fdot2(w.z, h.z, acc[rl]);
        acc[rl] = fdot2(w.w, h.w, acc[rl]);
      }
    }
    // slots 6,7: LDS weights
#pragma unroll
    for (int i = 6; i < 8; i++) {
      uint4 h = *(const uint4*)(hb + qoff[i]);
#pragma unroll
      for (int rl = 0; rl < 8; rl++) {
        uint4 lw = w_lds4[(rl * 2 + (i - 6)) * 512 + tid];
        acc[rl] = fdot2(lw.x, h.x, acc[rl]);
        acc[rl] = fdot2(lw.y, h.y, acc[rl]);
        acc[rl] = fdot2(lw.z, h.z, acc[rl]);
        acc[rl] = fdot2(lw.w, h.w, acc[rl]);
      }
    }
    // butterfly over s via DPP quad_perm (xor1 then xor2): all 4 lanes of a
    // quad end with identical full sums (commutative adds, bit-identical)
#pragma unroll
    for (int rl = 0; rl < 8; rl++) acc[rl] = dpp_add<0xB1>(acc[rl]);
#pragma unroll
    for (int rl = 0; rl < 8; rl++) acc[rl] = dpp_add<0x4E>(acc[rl]);

    // this lane's 4 gates (rows g*256 + u2 <-> acc[g*2+hh])
    float di = hh ? acc[1] : acc[0];
    float df = hh ? acc[3] : acc[2];
    float dc = hh ? acc[5] : acc[4];
    float do_ = hh ? acc[7] : acc[6];
    float g_i = ig0 + rb0 + m_ * di;
    float g_f = ig1 + rb1 + m_ * df;
    float g_c = ig2 + rb2 + m_ * dc;
    float g_o = ig3 + rb3 + m_ * do_;
    cx = sigm(g_f) * cx + sigm(g_i) * tanh_(g_c);
    float h_raw = sigm(g_o) * tanh_(cx);

    // hx write FIRST (keeps DS queue short before the barrier)
    if (s < 2) hx_buf[cur][u2] = f16b(h_raw);

    // attention partial: full-wave DPP sum -> lane 63
    float part = (s < 2) ? h_raw * awj : 0.f;
    part = dpp_add<0x111>(part);
    part = dpp_add<0x112>(part);
    part = dpp_add<0x114>(part);
    part = dpp_add<0x118>(part);
    part = dpp_add<0x142>(part);
    part = dpp_add<0x143>(part);
    if (lane == 63) red[cur][wid] = part;

    h_prev = h_raw;
    __syncthreads();
  }
  // flush last step (ungated)
  if (s < 2) {
    xnext[(b * 512 + 511) * 256 + u2] = f16b(h_prev);
    out[(((l + 1) * 32 + b) * 256 + u2) * 2 + 1] = h_prev;       // x w=511
    out[65536 + ((l * 32 + b) * 256 + u2) * 2 + 1] = cx;         // nc w=511
  }
}

extern "C" void kernel_launch(void* const* d_in, const int* in_sizes, int n_in,
                              void* d_out, int out_size, void* d_ws,
                              size_t ws_size, hipStream_t stream) {
  const float* input  = (const float*)d_in[0];
  const float* hidden = (const float*)d_in[1];
  const float* context= (const float*)d_in[2];
  const float* emb_w  = (const float*)d_in[3];
  const float* emb_b  = (const float*)d_in[4];
  const float* conv_w = (const float*)d_in[5];
  const float* conv_b = (const float*)d_in[6];
  const float* rec_w  = (const float*)d_in[7];
  const float* rec_b  = (const float*)d_in[8];
  const float* attn_w = (const float*)d_in[9];
  float* out = (float*)d_out;

  char* ws = (char*)d_ws;
  unsigned short* xf16 = (unsigned short*)ws;                    // 4 x 4,194,304 f16 = 32 MB
  _Float16* igf = (_Float16*)(ws + 33554432);                    // 16,777,216 f16 = 32 MB
  unsigned* rwp = (unsigned*)(ws + 67108864);                    // 1.5 MB
  unsigned* cwp = (unsigned*)(ws + 68681728);                    // 6 MB

  hipLaunchKernelGGL(prep_rw, dim3(1536), dim3(256), 0, stream, rec_w, rwp);
  hipLaunchKernelGGL(prep_cw, dim3(6144), dim3(256), 0, stream, conv_w, cwp);
  hipLaunchKernelGGL(emb_kernel, dim3(8, 4, 32), dim3(256), 0, stream,
                     input, emb_w, emb_b, xf16, out);
  int off = 0;
  for (int l = 0; l < 3; l++) {
    hipLaunchKernelGGL(conv_kernel, dim3(8, 16, 32), dim3(256), 0, stream,
                       xf16, cwp, conv_b, hidden, (unsigned short*)igf, l, off);
    hipLaunchKernelGGL(rec_kernel, dim3(32), dim3(512), 0, stream,
                       igf, rwp + l * 131072, rec_b + l * 1024,
                       attn_w + l * 256, hidden, context, l,
                       xf16 + (l + 1) * 4194304, out);
    off += l + 1;
  }
}